// Round 7
// baseline (173.541 us; speedup 1.0000x reference)
//
#include <hip/hip_runtime.h>
#include <math.h>

#define N_EXC   20000
#define N_KCC   1024
#define FDIM    128
#define LEAKY_S 0.2f

#define BR  32       // exercise rows per block
#define TJ  64       // kc (j) tile (16 tiles), double-buffered
#define EXS 136      // ex staging stride in ushorts (272 B)
#define WST 72       // w tile stride in ushorts (144 B)

typedef unsigned short ushort_t;
typedef __attribute__((ext_vector_type(8))) short short8;
typedef __attribute__((ext_vector_type(4))) float floatx4;

__device__ __forceinline__ ushort_t f2bf(float f) {
    unsigned u = __float_as_uint(f);
    u += 0x7FFF + ((u >> 16) & 1);          // RNE
    return (ushort_t)(u >> 16);
}

// async global->LDS, 16 B per lane. LDS dest must be wave-uniform base + lane*16.
__device__ __forceinline__ void async16(const void* g, void* l) {
    __builtin_amdgcn_global_load_lds(
        (const __attribute__((address_space(1))) unsigned int*)g,
        (__attribute__((address_space(3))) unsigned int*)l,
        16, 0, 0);
}

// ws layout (float offsets):
//   [0)     tarr  1024 f32
//   [1024)  w1a1  128 f32
//   [1152)  kc_sw 131072 ushorts (256 KB): 16 tiles x [f=128][c'=8][e=8],
//           tile jt = j>>6, chunk c = (j&63)>>3, c' = c ^ (f&7), val = bf16(kcWh[j][f])
//   [+256K) E_sw  16384 ushorts (32 KB): 2 halves (k<64, k>=64) x [n=128][c'=8][e=8]
//   [+32K)  W1T_sw 16384 ushorts (32 KB): [f=128][c'=16][e=8], c' = c ^ (f&15)
//   [+32K)  msk_sw 20000*32 uint32 (2.56 MB): per (row, jg=0..7) 16-byte record,
//           byte jt = bits e=0..7 for j = jt*64 + jg*8 + e  (little-endian in uint32)

// ---------------- adj compression: 82 MB -> 2.56 MB ----------------
__global__ __launch_bounds__(256) void gat_adj(const int* __restrict__ adj,
                                               float* __restrict__ ws)
{
    ushort_t* kc_sw  = (ushort_t*)(ws + N_KCC + FDIM);
    ushort_t* E_sw   = kc_sw + FDIM * N_KCC;
    ushort_t* W1T_sw = E_sw + FDIM * FDIM;
    unsigned* msk_sw = (unsigned*)(W1T_sw + FDIM * FDIM);

    __shared__ unsigned char ml[8 * 8 * 16];   // [r_loc][jg][jt] bytes, 1 KB

    const int tid = threadIdx.x;
    const int r_loc = tid >> 5, seg = tid & 31;        // seg: 32-j segment of the row
    const size_t r = (size_t)blockIdx.x * 8 + r_loc;
    const int4* p = (const int4*)(adj + r * N_KCC + seg * 32);
    const int jt = seg >> 1;
    #pragma unroll
    for (int q = 0; q < 4; ++q) {
        int4 a0 = p[q * 2 + 0];
        int4 a1 = p[q * 2 + 1];
        unsigned m = (a0.x > 0 ? 1u : 0u)
                   | (a0.y > 0 ? 2u : 0u)
                   | (a0.z > 0 ? 4u : 0u)
                   | (a0.w > 0 ? 8u : 0u)
                   | (a1.x > 0 ? 16u : 0u)
                   | (a1.y > 0 ? 32u : 0u)
                   | (a1.z > 0 ? 64u : 0u)
                   | (a1.w > 0 ? 128u : 0u);
        int jg = (seg & 1) * 4 + q;
        ml[(r_loc * 8 + jg) * 16 + jt] = (unsigned char)m;
    }
    __syncthreads();
    if (tid < 64) {
        uint4 v = *(const uint4*)(ml + tid * 16);
        *(uint4*)(msk_sw + (size_t)blockIdx.x * 256 + tid * 4) = v;
    }
}

// ---------------- prep0: W1 transpose (+w1a1) and E swizzle ----------------
__global__ __launch_bounds__(256) void gat_prep0(const float* __restrict__ W1,
                                                 const float* __restrict__ E,
                                                 const float* __restrict__ a,
                                                 float* __restrict__ ws)
{
    float* w1a1 = ws + N_KCC;
    ushort_t* kc_sw  = (ushort_t*)(ws + N_KCC + FDIM);
    ushort_t* E_sw   = kc_sw + FDIM * N_KCC;
    ushort_t* W1T_sw = E_sw + FDIM * FDIM;
    const int tid = threadIdx.x;

    if (blockIdx.x == 1) {
        // E_sw, two k-halves, c' = ((k&63)>>3) ^ (n&7)
        #pragma unroll
        for (int u = 0; u < 8; ++u) {
            int ch = u * 256 + tid;              // 0..2047 chunks
            int half = ch >> 10;
            int rem = ch & 1023;
            int n = rem >> 3, cpp = rem & 7;
            int c = cpp ^ (n & 7);
            int kbase = half * 64 + c * 8;
            unsigned pk[4];
            #pragma unroll
            for (int i = 0; i < 4; ++i) {
                float e0 = E[(kbase + 2 * i + 0) * FDIM + n];
                float e1 = E[(kbase + 2 * i + 1) * FDIM + n];
                pk[i] = (unsigned)f2bf(e0) | ((unsigned)f2bf(e1) << 16);
            }
            *(uint4*)(E_sw + ch * 8) = make_uint4(pk[0], pk[1], pk[2], pk[3]);
        }
        return;
    }

    // block 0: W1 -> LDS (fp32), then transposed swizzled bf16 to ws; w1a1
    __shared__ __align__(16) float w1f[128 * 132];   // 67.6 KB, k-major
    __shared__ float a_lds[2 * FDIM];
    #pragma unroll
    for (int u = 0; u < 16; ++u) {
        int flat = u * 256 + tid;
        int k = flat >> 5, c4 = (flat & 31) * 4;
        float4 v = *(const float4*)(W1 + k * FDIM + c4);
        w1f[k * 132 + c4 + 0] = v.x; w1f[k * 132 + c4 + 1] = v.y;
        w1f[k * 132 + c4 + 2] = v.z; w1f[k * 132 + c4 + 3] = v.w;
    }
    a_lds[tid] = a[tid];
    __syncthreads();
    // W1T_sw chunks: [f][c'] with c' = c ^ (f&15)
    #pragma unroll
    for (int u = 0; u < 8; ++u) {
        int ch = u * 256 + tid;          // 0..2047
        int f = ch >> 4, c = ch & 15;
        unsigned pk[4];
        #pragma unroll
        for (int i = 0; i < 4; ++i) {
            float v0 = w1f[(c * 8 + 2 * i + 0) * 132 + f];
            float v1 = w1f[(c * 8 + 2 * i + 1) * 132 + f];
            pk[i] = (unsigned)f2bf(v0) | ((unsigned)f2bf(v1) << 16);
        }
        *(uint4*)(W1T_sw + f * 128 + (c ^ (f & 15)) * 8) = make_uint4(pk[0], pk[1], pk[2], pk[3]);
    }
    if (tid < FDIM) {
        float acc = 0.f;
        #pragma unroll 8
        for (int f = 0; f < FDIM; ++f) acc += w1f[tid * 132 + f] * a_lds[f];
        w1a1[tid] = acc;
    }
}

// ---------------- prep1: kcWh via MFMA + fused t[j] ----------------
__global__ __launch_bounds__(256) void gat_prep1(const float* __restrict__ kc_h,
                                                 const float* __restrict__ a,
                                                 float* __restrict__ ws)
{
    float* tarr = ws;
    ushort_t* kc_sw  = (ushort_t*)(ws + N_KCC + FDIM);
    ushort_t* E_sw   = kc_sw + FDIM * N_KCC;
    const ushort_t* W1T_sw = E_sw + FDIM * FDIM;

    __shared__ __align__(16) ushort_t w1t[128 * 128];   // 32 KB pre-swizzled
    __shared__ __align__(16) ushort_t outt[128 * 16];   // 4 KB  [f][j-local]
    __shared__ float a2_lds[FDIM];
    __shared__ float scrT[256];

    const int tid = threadIdx.x;
    const int b = blockIdx.x;
    const int j0 = b * 16;
    const int jt = b >> 2;
    const int c0 = (b & 3) * 2;
    const int lane = tid & 63, w = tid >> 6;
    const int l15 = lane & 15, quad = lane >> 4;

    // async-stage W1T (flat copy, pre-swizzled)
    #pragma unroll
    for (int u = 0; u < 8; ++u) {
        int ci = u * 256 + tid;
        async16(W1T_sw + ci * 8, w1t + ci * 8);
    }
    if (tid < FDIM) a2_lds[tid] = a[FDIM + tid];

    // B-fragments: kc_h[j0+l15][k] global -> regs -> bf16 (k-contiguous)
    short8 bfrag[4];
    #pragma unroll
    for (int kk = 0; kk < 4; ++kk) {
        const float* p = kc_h + (size_t)(j0 + l15) * FDIM + kk * 32 + quad * 8;
        float4 x = *(const float4*)(p);
        float4 y = *(const float4*)(p + 4);
        float v[8] = {x.x, x.y, x.z, x.w, y.x, y.y, y.z, y.w};
        unsigned pk[4];
        #pragma unroll
        for (int i = 0; i < 4; ++i)
            pk[i] = (unsigned)f2bf(v[2 * i]) | ((unsigned)f2bf(v[2 * i + 1]) << 16);
        uint4 q = make_uint4(pk[0], pk[1], pk[2], pk[3]);
        bfrag[kk] = *(const short8*)&q;
    }
    __syncthreads();   // drains W1T async + a2 stage

    // C[m=f-local][n=j-local] = sum_k W1[k][f] * kc[j][k]
    floatx4 acc[2];
    acc[0] = (floatx4){0.f, 0.f, 0.f, 0.f};
    acc[1] = (floatx4){0.f, 0.f, 0.f, 0.f};
    #pragma unroll
    for (int kk = 0; kk < 4; ++kk) {
        #pragma unroll
        for (int g = 0; g < 2; ++g) {
            int f = w * 32 + g * 16 + l15;
            int cp = (kk * 4 + quad) ^ l15;
            short8 af = *(const short8*)(w1t + f * 128 + cp * 8);
            acc[g] = __builtin_amdgcn_mfma_f32_16x16x32_bf16(af, bfrag[kk], acc[g], 0, 0, 0);
        }
    }

    // epilogue: bf16 transpose tile + fused t partials
    float tp = 0.f;
    #pragma unroll
    for (int g = 0; g < 2; ++g)
        #pragma unroll
        for (int reg = 0; reg < 4; ++reg) {
            int f = w * 32 + g * 16 + quad * 4 + reg;
            outt[f * 16 + l15] = f2bf(acc[g][reg]);
            tp += acc[g][reg] * a2_lds[f];
        }
    scrT[l15 * 16 + w * 4 + quad] = tp;
    __syncthreads();

    // coalesced swizzled stores to kc_sw
    {
        int f = tid >> 1, hf = tid & 1;
        uint4 v = *(const uint4*)(outt + f * 16 + hf * 8);
        int cp = (c0 + hf) ^ (f & 7);
        *(uint4*)(kc_sw + (size_t)jt * 8192 + f * 64 + cp * 8) = v;
    }
    if (tid < 16) {
        float s = 0.f;
        #pragma unroll
        for (int p = 0; p < 16; ++p) s += scrT[tid * 16 + p];
        tarr[j0 + tid] = s;
    }
}

// ---------------- main ----------------
__global__ __launch_bounds__(256, 3) void gat_main(const float* __restrict__ ex_h,
                                                   const float* __restrict__ ws,
                                                   float* __restrict__ out)
{
    const float* tarr = ws;
    const float* w1a1 = ws + N_KCC;
    const ushort_t* kc_sw = (const ushort_t*)(ws + N_KCC + FDIM);
    const ushort_t* E_sw  = kc_sw + FDIM * N_KCC;
    const ushort_t* W1T_sw = E_sw + FDIM * FDIM;
    const unsigned* msk_sw = (const unsigned*)(W1T_sw + FDIM * FDIM);

    __shared__ __align__(16) float t_lds[N_KCC];          // 4 KB
    __shared__ __align__(16) ushort_t kc_lds[2 * 8192];   // 32 KB (E prologue / kc dbuf)
    __shared__ __align__(16) ushort_t ww_lds[4608];       // 9.2 KB (ex staging / w dbuf)
    __shared__ __align__(16) float scrA[256];
    __shared__ __align__(16) float scrB[256];
    __shared__ float w1a1_lds[FDIM];
    __shared__ float s_lds[BR], m_lds[BR], denom_lds[BR];

    const int tid  = threadIdx.x;
    const int R0   = blockIdx.x * BR;
    const int lane = tid & 63, wid = tid >> 6;
    const int l15  = lane & 15, quad = lane >> 4;

    // ---- issue E async load first (32 KB flat) ----
    #pragma unroll
    for (int u = 0; u < 8; ++u) {
        int ci = u * 256 + tid;
        async16(E_sw + ci * 8, kc_lds + ci * 8);
    }

    // ---- stage t, w1a1, ex rows ----
    #pragma unroll
    for (int u = 0; u < 4; ++u) t_lds[u * 256 + tid] = tarr[u * 256 + tid];
    if (tid < FDIM) w1a1_lds[tid] = w1a1[tid];
    const int r0 = tid >> 3;
    const int fc = (tid & 7) * 16;
    float exv[16];
    {
        const float* src = ex_h + (size_t)(R0 + r0) * FDIM + fc;
        #pragma unroll
        for (int c = 0; c < 4; ++c) {
            float4 v = *(const float4*)(src + c * 4);
            exv[c * 4 + 0] = v.x; exv[c * 4 + 1] = v.y;
            exv[c * 4 + 2] = v.z; exv[c * 4 + 3] = v.w;
        }
        unsigned pk[8];
        #pragma unroll
        for (int i = 0; i < 8; ++i)
            pk[i] = (unsigned)f2bf(exv[2 * i]) | ((unsigned)f2bf(exv[2 * i + 1]) << 16);
        *(uint4*)(ww_lds + r0 * EXS + fc)     = make_uint4(pk[0], pk[1], pk[2], pk[3]);
        *(uint4*)(ww_lds + r0 * EXS + fc + 8) = make_uint4(pk[4], pk[5], pk[6], pk[7]);
    }

    // ---- adj bitmask record: ONE 16-B load per thread (was 32x int4) ----
    const int r_w = tid >> 3;          // w row
    const int jg  = tid & 7;           // 8-j chunk within tile
    unsigned msk[4];
    {
        uint4 mv = *(const uint4*)(msk_sw + ((size_t)(R0 + r_w) * 8 + jg) * 4);
        msk[0] = mv.x; msk[1] = mv.y; msk[2] = mv.z; msk[3] = mv.w;
    }
    __syncthreads();   // drains E async; publishes t/ex/w1a1

    // ---- Tmax + s partials ----
    {
        float mx = fmaxf(fmaxf(t_lds[tid], t_lds[256 + tid]),
                         fmaxf(t_lds[512 + tid], t_lds[768 + tid]));
        scrB[tid] = mx;
        float p = 0.f;
        #pragma unroll
        for (int i = 0; i < 16; ++i) p += exv[i] * w1a1_lds[fc + i];
        scrA[tid] = p;
    }
    __syncthreads();
    if (tid < 64)
        scrB[tid] = fmaxf(fmaxf(scrB[tid], scrB[tid + 64]),
                          fmaxf(scrB[tid + 128], scrB[tid + 192]));
    __syncthreads();
    if (tid < BR) {
        float Tm = scrB[0];
        #pragma unroll 8
        for (int i = 1; i < 64; ++i) Tm = fmaxf(Tm, scrB[i]);
        float s = 0.f;
        #pragma unroll
        for (int g = 0; g < 8; ++g) s += scrA[tid * 8 + g];
        s_lds[tid] = s;
        float x = s + Tm;
        m_lds[tid] = (x >= 0.f) ? x : LEAKY_S * x;
    }
    __syncthreads();   // publish s_lds/m_lds (R3 lesson: required)

    // ---- Eh = ex @ E via MFMA (E in kc_lds both halves, swizzled) ----
    floatx4 eh_acc[2][2], att_acc[2][2];
    #pragma unroll
    for (int mg = 0; mg < 2; ++mg)
        #pragma unroll
        for (int h = 0; h < 2; ++h) {
            eh_acc[mg][h]  = (floatx4){0.f, 0.f, 0.f, 0.f};
            att_acc[mg][h] = (floatx4){0.f, 0.f, 0.f, 0.f};
        }
    #pragma unroll
    for (int kk = 0; kk < 4; ++kk) {
        short8 a0 = *(const short8*)(ww_lds + l15 * EXS + kk * 32 + quad * 8);
        short8 a1 = *(const short8*)(ww_lds + (16 + l15) * EXS + kk * 32 + quad * 8);
        #pragma unroll
        for (int h = 0; h < 2; ++h) {
            const int n = (h * 4 + wid) * 16 + l15;
            const int cpp = ((kk & 1) * 4 + quad) ^ (n & 7);
            short8 bf = *(const short8*)(kc_lds + (kk >> 1) * 8192 + n * 64 + cpp * 8);
            eh_acc[0][h] = __builtin_amdgcn_mfma_f32_16x16x32_bf16(a0, bf, eh_acc[0][h], 0, 0, 0);
            eh_acc[1][h] = __builtin_amdgcn_mfma_f32_16x16x32_bf16(a1, bf, eh_acc[1][h], 0, 0, 0);
        }
    }
    __syncthreads();   // barrier B1: Eh LDS reads done; kc_lds/ww_lds reusable

    // ---- w generation helper state ----
    const float sr = s_lds[r_w];
    const float mr = m_lds[r_w];
    float denom_part = 0.f;

    // gen w tile jt into buffer wb
    auto genw = [&](int jt, ushort_t* wb) {
        const int jb = jt * TJ + jg * 8;
        float4 ta = *(const float4*)(t_lds + jb);
        float4 tb = *(const float4*)(t_lds + jb + 4);
        float tv[8] = {ta.x, ta.y, ta.z, ta.w, tb.x, tb.y, tb.z, tb.w};
        unsigned mb = msk[jt >> 2] >> ((jt & 3) * 8);
        float wv[8];
        #pragma unroll
        for (int e = 0; e < 8; ++e) {
            float x = sr + tv[e];
            x = fmaxf(x, LEAKY_S * x);
            float w = __expf(x - mr);
            w = ((mb >> e) & 1u) ? w : 0.f;
            denom_part += w;
            wv[e] = w;
        }
        unsigned pk[4];
        #pragma unroll
        for (int i = 0; i < 4; ++i) {
            unsigned ua = __float_as_uint(wv[2 * i + 0]) + 0x8000u;
            unsigned ub = __float_as_uint(wv[2 * i + 1]) + 0x8000u;
            pk[i] = __builtin_amdgcn_perm(ub, ua, 0x07060302);
        }
        *(uint4*)(wb + r_w * WST + jg * 8) = make_uint4(pk[0], pk[1], pk[2], pk[3]);
    };

    // ---- pipeline prologue: kc[0] async + w[0] ----
    #pragma unroll
    for (int u = 0; u < 4; ++u) {
        int ci = u * 256 + tid;
        async16(kc_sw + ci * 8, kc_lds + ci * 8);
    }
    genw(0, ww_lds);
    __syncthreads();   // barrier B2: kc[0] + w[0] ready

    // ---- main j loop: 16 tiles, one barrier each, double-buffered ----
    for (int jt = 0; jt < N_KCC / TJ; ++jt) {
        if (jt < 15) {
            const ushort_t* gsrc = kc_sw + (size_t)(jt + 1) * 8192;
            ushort_t* kdst = kc_lds + ((jt + 1) & 1) * 8192;
            #pragma unroll
            for (int u = 0; u < 4; ++u) {
                int ci = u * 256 + tid;
                async16(gsrc + ci * 8, kdst + ci * 8);
            }
            genw(jt + 1, ww_lds + ((jt + 1) & 1) * 2304);
        }
        // MFMA tile jt
        const ushort_t* kcb = kc_lds + (jt & 1) * 8192;
        const ushort_t* wb  = ww_lds + (jt & 1) * 2304;
        #pragma unroll
        for (int kk = 0; kk < 2; ++kk) {
            short8 a0 = *(const short8*)(wb + l15 * WST + kk * 32 + quad * 8);
            short8 a1 = *(const short8*)(wb + (16 + l15) * WST + kk * 32 + quad * 8);
            #pragma unroll
            for (int h = 0; h < 2; ++h) {
                const int f = (h * 4 + wid) * 16 + l15;
                const int cpp = (kk * 4 + quad) ^ (f & 7);
                short8 bf = *(const short8*)(kcb + f * 64 + cpp * 8);
                att_acc[0][h] = __builtin_amdgcn_mfma_f32_16x16x32_bf16(a0, bf, att_acc[0][h], 0, 0, 0);
                att_acc[1][h] = __builtin_amdgcn_mfma_f32_16x16x32_bf16(a1, bf, att_acc[1][h], 0, 0, 0);
            }
        }
        __syncthreads();   // next tile's kc/w ready; this tile's reads done
    }

    // ---- denominator reduce ----
    scrA[tid] = denom_part;
    __syncthreads();
    if (tid < BR) {
        float d = 0.f;
        #pragma unroll
        for (int g = 0; g < 8; ++g) d += scrA[tid * 8 + g];
        denom_lds[tid] = (d > 0.f) ? d : 1.f;
    }
    __syncthreads();

    // ---- epilogue: normalize * Eh, elu, store (C-layout: col=l15, row=quad*4+reg) ----
    #pragma unroll
    for (int mg = 0; mg < 2; ++mg) {
        float rd[4];
        #pragma unroll
        for (int reg = 0; reg < 4; ++reg)
            rd[reg] = 1.f / denom_lds[mg * 16 + quad * 4 + reg];
        #pragma unroll
        for (int h = 0; h < 2; ++h) {
            const int col = (h * 4 + wid) * 16 + l15;
            #pragma unroll
            for (int reg = 0; reg < 4; ++reg) {
                const int rl = mg * 16 + quad * 4 + reg;
                float v = att_acc[mg][h][reg] * rd[reg] * eh_acc[mg][h][reg];
                out[(size_t)(R0 + rl) * FDIM + col] = (v > 0.f) ? v : expm1f(v);
            }
        }
    }
}

extern "C" void kernel_launch(void* const* d_in, const int* in_sizes, int n_in,
                              void* d_out, int out_size, void* d_ws, size_t ws_size,
                              hipStream_t stream)
{
    const float* ex_h = (const float*)d_in[0];
    const float* kc_h = (const float*)d_in[1];
    const int*   adj  = (const int*)d_in[2];
    const float* W1   = (const float*)d_in[3];
    const float* E    = (const float*)d_in[4];
    const float* a    = (const float*)d_in[5];
    float* outp = (float*)d_out;
    float* ws   = (float*)d_ws;

    gat_adj<<<N_EXC / 8, 256, 0, stream>>>(adj, ws);
    gat_prep0<<<2, 256, 0, stream>>>(W1, E, a, ws);
    gat_prep1<<<64, 256, 0, stream>>>(kc_h, a, ws);
    gat_main<<<N_EXC / BR, 256, 0, stream>>>(ex_h, ws, outp);
}

// Round 8
// 166.627 us; speedup vs baseline: 1.0415x; 1.0415x over previous
//
#include <hip/hip_runtime.h>
#include <math.h>

#define N_EXC   20000
#define N_KCC   1024
#define FDIM    128
#define LEAKY_S 0.2f

#define BR  32       // exercise rows per block
#define TJ  64       // kc (j) tile (16 tiles), double-buffered
#define EXS 136      // ex staging stride in ushorts (272 B)
#define WST 72       // w tile stride in ushorts (144 B)

typedef unsigned short ushort_t;
typedef __attribute__((ext_vector_type(8))) short short8;
typedef __attribute__((ext_vector_type(4))) float floatx4;

__device__ __forceinline__ ushort_t f2bf(float f) {
    unsigned u = __float_as_uint(f);
    u += 0x7FFF + ((u >> 16) & 1);          // RNE
    return (ushort_t)(u >> 16);
}

// async global->LDS, 16 B per lane. LDS dest must be wave-uniform base + lane*16.
__device__ __forceinline__ void async16(const void* g, void* l) {
    __builtin_amdgcn_global_load_lds(
        (const __attribute__((address_space(1))) unsigned int*)g,
        (__attribute__((address_space(3))) unsigned int*)l,
        16, 0, 0);
}

// ws layout (float offsets):
//   [0)     tarr  1024 f32
//   [1024)  w1a1  128 f32
//   [1152)  kc_sw 131072 ushorts (256 KB): 16 tiles x [f=128][c'=8][e=8],
//           tile jt = j>>6, chunk c = (j&63)>>3, c' = c ^ (f&7), val = bf16(kcWh[j][f])
//   [+256K) E_sw  16384 ushorts (32 KB): 2 halves (k<64, k>=64) x [n=128][c'=8][e=8]
//   [+32K)  W1T_sw 16384 ushorts (32 KB): [f=128][c'=16][e=8], c' = c ^ (f&15)
//   [+32K)  msk_sw 20000*32 uint32 (2.56 MB): per (row, jg=0..7) 16-byte record,
//           byte jt = bits e=0..7 for j = jt*64 + jg*8 + e  (little-endian in uint32)

// -------- setup: adj compression (b<2500) + W1 transpose/w1a1 (b==2500) + E swizzle (b==2501)
__global__ __launch_bounds__(256) void gat_setup(const int* __restrict__ adj,
                                                 const float* __restrict__ W1,
                                                 const float* __restrict__ E,
                                                 const float* __restrict__ a,
                                                 float* __restrict__ ws)
{
    float* w1a1 = ws + N_KCC;
    ushort_t* kc_sw  = (ushort_t*)(ws + N_KCC + FDIM);
    ushort_t* E_sw   = kc_sw + FDIM * N_KCC;
    ushort_t* W1T_sw = E_sw + FDIM * FDIM;
    unsigned* msk_sw = (unsigned*)(W1T_sw + FDIM * FDIM);

    __shared__ __align__(16) float w1f[128 * 132];   // 67.6 KB (prep path; aliased by adj path)
    __shared__ float a_lds[2 * FDIM];

    const int tid = threadIdx.x;
    const int b = blockIdx.x;

    if (b < 2500) {
        // ---- adj compression: 8 rows/block, 82 MB -> 2.56 MB ----
        unsigned char* ml = (unsigned char*)w1f;       // [r_loc][jg][jt] bytes, 1 KB
        const int r_loc = tid >> 5, seg = tid & 31;    // seg: 32-j segment of the row
        const size_t r = (size_t)b * 8 + r_loc;
        const int4* p = (const int4*)(adj + r * N_KCC + seg * 32);
        const int jt = seg >> 1;
        #pragma unroll
        for (int q = 0; q < 4; ++q) {
            int4 a0 = p[q * 2 + 0];
            int4 a1 = p[q * 2 + 1];
            unsigned m = (a0.x > 0 ? 1u : 0u)
                       | (a0.y > 0 ? 2u : 0u)
                       | (a0.z > 0 ? 4u : 0u)
                       | (a0.w > 0 ? 8u : 0u)
                       | (a1.x > 0 ? 16u : 0u)
                       | (a1.y > 0 ? 32u : 0u)
                       | (a1.z > 0 ? 64u : 0u)
                       | (a1.w > 0 ? 128u : 0u);
            int jg = (seg & 1) * 4 + q;
            ml[(r_loc * 8 + jg) * 16 + jt] = (unsigned char)m;
        }
        __syncthreads();
        if (tid < 64) {
            uint4 v = *(const uint4*)(ml + tid * 16);
            *(uint4*)(msk_sw + (size_t)b * 256 + tid * 4) = v;
        }
        return;
    }

    if (b == 2501) {
        // ---- E_sw, two k-halves, c' = ((k&63)>>3) ^ (n&7) ----
        #pragma unroll
        for (int u = 0; u < 8; ++u) {
            int ch = u * 256 + tid;              // 0..2047 chunks
            int half = ch >> 10;
            int rem = ch & 1023;
            int n = rem >> 3, cpp = rem & 7;
            int c = cpp ^ (n & 7);
            int kbase = half * 64 + c * 8;
            unsigned pk[4];
            #pragma unroll
            for (int i = 0; i < 4; ++i) {
                float e0 = E[(kbase + 2 * i + 0) * FDIM + n];
                float e1 = E[(kbase + 2 * i + 1) * FDIM + n];
                pk[i] = (unsigned)f2bf(e0) | ((unsigned)f2bf(e1) << 16);
            }
            *(uint4*)(E_sw + ch * 8) = make_uint4(pk[0], pk[1], pk[2], pk[3]);
        }
        return;
    }

    // ---- b == 2500: W1 -> LDS (fp32), transposed swizzled bf16 to ws; w1a1 ----
    #pragma unroll
    for (int u = 0; u < 16; ++u) {
        int flat = u * 256 + tid;
        int k = flat >> 5, c4 = (flat & 31) * 4;
        float4 v = *(const float4*)(W1 + k * FDIM + c4);
        w1f[k * 132 + c4 + 0] = v.x; w1f[k * 132 + c4 + 1] = v.y;
        w1f[k * 132 + c4 + 2] = v.z; w1f[k * 132 + c4 + 3] = v.w;
    }
    a_lds[tid] = a[tid];
    __syncthreads();
    #pragma unroll
    for (int u = 0; u < 8; ++u) {
        int ch = u * 256 + tid;          // 0..2047
        int f = ch >> 4, c = ch & 15;
        unsigned pk[4];
        #pragma unroll
        for (int i = 0; i < 4; ++i) {
            float v0 = w1f[(c * 8 + 2 * i + 0) * 132 + f];
            float v1 = w1f[(c * 8 + 2 * i + 1) * 132 + f];
            pk[i] = (unsigned)f2bf(v0) | ((unsigned)f2bf(v1) << 16);
        }
        *(uint4*)(W1T_sw + f * 128 + (c ^ (f & 15)) * 8) = make_uint4(pk[0], pk[1], pk[2], pk[3]);
    }
    if (tid < FDIM) {
        float acc = 0.f;
        #pragma unroll 8
        for (int f = 0; f < FDIM; ++f) acc += w1f[tid * 132 + f] * a_lds[f];
        w1a1[tid] = acc;
    }
}

// ---------------- prep1: kcWh via MFMA + fused t[j] ----------------
__global__ __launch_bounds__(256) void gat_prep1(const float* __restrict__ kc_h,
                                                 const float* __restrict__ a,
                                                 float* __restrict__ ws)
{
    float* tarr = ws;
    ushort_t* kc_sw  = (ushort_t*)(ws + N_KCC + FDIM);
    ushort_t* E_sw   = kc_sw + FDIM * N_KCC;
    const ushort_t* W1T_sw = E_sw + FDIM * FDIM;

    __shared__ __align__(16) ushort_t w1t[128 * 128];   // 32 KB pre-swizzled
    __shared__ __align__(16) ushort_t outt[128 * 16];   // 4 KB  [f][j-local]
    __shared__ float a2_lds[FDIM];
    __shared__ float scrT[256];

    const int tid = threadIdx.x;
    const int b = blockIdx.x;
    const int j0 = b * 16;
    const int jt = b >> 2;
    const int c0 = (b & 3) * 2;
    const int lane = tid & 63, w = tid >> 6;
    const int l15 = lane & 15, quad = lane >> 4;

    // async-stage W1T (flat copy, pre-swizzled)
    #pragma unroll
    for (int u = 0; u < 8; ++u) {
        int ci = u * 256 + tid;
        async16(W1T_sw + ci * 8, w1t + ci * 8);
    }
    if (tid < FDIM) a2_lds[tid] = a[FDIM + tid];

    // B-fragments: kc_h[j0+l15][k] global -> regs -> bf16 (k-contiguous)
    short8 bfrag[4];
    #pragma unroll
    for (int kk = 0; kk < 4; ++kk) {
        const float* p = kc_h + (size_t)(j0 + l15) * FDIM + kk * 32 + quad * 8;
        float4 x = *(const float4*)(p);
        float4 y = *(const float4*)(p + 4);
        float v[8] = {x.x, x.y, x.z, x.w, y.x, y.y, y.z, y.w};
        unsigned pk[4];
        #pragma unroll
        for (int i = 0; i < 4; ++i)
            pk[i] = (unsigned)f2bf(v[2 * i]) | ((unsigned)f2bf(v[2 * i + 1]) << 16);
        uint4 q = make_uint4(pk[0], pk[1], pk[2], pk[3]);
        bfrag[kk] = *(const short8*)&q;
    }
    __syncthreads();   // drains W1T async + a2 stage

    // C[m=f-local][n=j-local] = sum_k W1[k][f] * kc[j][k]
    floatx4 acc[2];
    acc[0] = (floatx4){0.f, 0.f, 0.f, 0.f};
    acc[1] = (floatx4){0.f, 0.f, 0.f, 0.f};
    #pragma unroll
    for (int kk = 0; kk < 4; ++kk) {
        #pragma unroll
        for (int g = 0; g < 2; ++g) {
            int f = w * 32 + g * 16 + l15;
            int cp = (kk * 4 + quad) ^ l15;
            short8 af = *(const short8*)(w1t + f * 128 + cp * 8);
            acc[g] = __builtin_amdgcn_mfma_f32_16x16x32_bf16(af, bfrag[kk], acc[g], 0, 0, 0);
        }
    }

    // epilogue: bf16 transpose tile + fused t partials
    float tp = 0.f;
    #pragma unroll
    for (int g = 0; g < 2; ++g)
        #pragma unroll
        for (int reg = 0; reg < 4; ++reg) {
            int f = w * 32 + g * 16 + quad * 4 + reg;
            outt[f * 16 + l15] = f2bf(acc[g][reg]);
            tp += acc[g][reg] * a2_lds[f];
        }
    scrT[l15 * 16 + w * 4 + quad] = tp;
    __syncthreads();

    // coalesced swizzled stores to kc_sw
    {
        int f = tid >> 1, hf = tid & 1;
        uint4 v = *(const uint4*)(outt + f * 16 + hf * 8);
        int cp = (c0 + hf) ^ (f & 7);
        *(uint4*)(kc_sw + (size_t)jt * 8192 + f * 64 + cp * 8) = v;
    }
    if (tid < 16) {
        float s = 0.f;
        #pragma unroll
        for (int p = 0; p < 16; ++p) s += scrT[tid * 16 + p];
        tarr[j0 + tid] = s;
    }
}

// ---------------- main ----------------
__global__ __launch_bounds__(256, 3) void gat_main(const float* __restrict__ ex_h,
                                                   const float* __restrict__ ws,
                                                   float* __restrict__ out)
{
    const float* tarr = ws;
    const float* w1a1 = ws + N_KCC;
    const ushort_t* kc_sw = (const ushort_t*)(ws + N_KCC + FDIM);
    const ushort_t* E_sw  = kc_sw + FDIM * N_KCC;
    const ushort_t* W1T_sw = E_sw + FDIM * FDIM;
    const unsigned* msk_sw = (const unsigned*)(W1T_sw + FDIM * FDIM);

    __shared__ __align__(16) float t_lds[N_KCC];          // 4 KB
    __shared__ __align__(16) ushort_t kc_lds[2 * 8192];   // 32 KB (E prologue / kc dbuf)
    __shared__ __align__(16) ushort_t ww_lds[4608];       // 9.2 KB (ex staging / w dbuf)
    __shared__ __align__(16) float scrA[BR];              // per-row s partials
    __shared__ __align__(16) float scrD[256];             // denom partials
    __shared__ float scrB[4];                             // per-wave t-max
    __shared__ float s_lds[BR], m_lds[BR], denom_lds[BR];

    const int tid  = threadIdx.x;
    const int R0   = blockIdx.x * BR;
    const int lane = tid & 63, wid = tid >> 6;
    const int l15  = lane & 15, quad = lane >> 4;

    // ---- issue E async load first (32 KB flat) ----
    #pragma unroll
    for (int u = 0; u < 8; ++u) {
        int ci = u * 256 + tid;
        async16(E_sw + ci * 8, kc_lds + ci * 8);
    }

    // ---- stage t (with running max), ex rows ----
    float tmx = -1e30f;
    #pragma unroll
    for (int u = 0; u < 4; ++u) {
        float tv = tarr[u * 256 + tid];
        t_lds[u * 256 + tid] = tv;
        tmx = fmaxf(tmx, tv);
    }
    const int r0 = tid >> 3;
    const int fc = (tid & 7) * 16;
    float exv[16];
    {
        const float* src = ex_h + (size_t)(R0 + r0) * FDIM + fc;
        #pragma unroll
        for (int c = 0; c < 4; ++c) {
            float4 v = *(const float4*)(src + c * 4);
            exv[c * 4 + 0] = v.x; exv[c * 4 + 1] = v.y;
            exv[c * 4 + 2] = v.z; exv[c * 4 + 3] = v.w;
        }
        unsigned pk[8];
        #pragma unroll
        for (int i = 0; i < 8; ++i)
            pk[i] = (unsigned)f2bf(exv[2 * i]) | ((unsigned)f2bf(exv[2 * i + 1]) << 16);
        *(uint4*)(ww_lds + r0 * EXS + fc)     = make_uint4(pk[0], pk[1], pk[2], pk[3]);
        *(uint4*)(ww_lds + r0 * EXS + fc + 8) = make_uint4(pk[4], pk[5], pk[6], pk[7]);
    }

    // ---- adj bitmask record: ONE 16-B load per thread ----
    const int r_w = tid >> 3;          // w row
    const int jg  = tid & 7;           // 8-j chunk within tile
    unsigned msk[4];
    {
        uint4 mv = *(const uint4*)(msk_sw + ((size_t)(R0 + r_w) * 8 + jg) * 4);
        msk[0] = mv.x; msk[1] = mv.y; msk[2] = mv.z; msk[3] = mv.w;
    }

    // ---- Tmax: wave shfl-reduce; s-partials: width-8 shfl-reduce ----
    #pragma unroll
    for (int d = 32; d > 0; d >>= 1)
        tmx = fmaxf(tmx, __shfl_down(tmx, d, 64));
    if (lane == 0) scrB[wid] = tmx;
    {
        float p = 0.f;
        #pragma unroll
        for (int i = 0; i < 16; ++i) p += exv[i] * w1a1[fc + i];   // w1a1 from L2 (512 B, hot)
        p += __shfl_down(p, 4, 8);
        p += __shfl_down(p, 2, 8);
        p += __shfl_down(p, 1, 8);
        if ((tid & 7) == 0) scrA[r0] = p;
    }
    __syncthreads();   // S1: drains E async; publishes t/ex LDS, scrA/scrB

    if (tid < BR) {
        float Tm = fmaxf(fmaxf(scrB[0], scrB[1]), fmaxf(scrB[2], scrB[3]));
        float s = scrA[tid];
        s_lds[tid] = s;
        float x = s + Tm;
        m_lds[tid] = (x >= 0.f) ? x : LEAKY_S * x;
    }
    __syncthreads();   // S2: publish s_lds/m_lds (R3 lesson: required)

    // ---- Eh = ex @ E via MFMA (E in kc_lds both halves, swizzled) ----
    floatx4 eh_acc[2][2], att_acc[2][2];
    #pragma unroll
    for (int mg = 0; mg < 2; ++mg)
        #pragma unroll
        for (int h = 0; h < 2; ++h) {
            eh_acc[mg][h]  = (floatx4){0.f, 0.f, 0.f, 0.f};
            att_acc[mg][h] = (floatx4){0.f, 0.f, 0.f, 0.f};
        }
    #pragma unroll
    for (int kk = 0; kk < 4; ++kk) {
        short8 a0 = *(const short8*)(ww_lds + l15 * EXS + kk * 32 + quad * 8);
        short8 a1 = *(const short8*)(ww_lds + (16 + l15) * EXS + kk * 32 + quad * 8);
        #pragma unroll
        for (int h = 0; h < 2; ++h) {
            const int n = (h * 4 + wid) * 16 + l15;
            const int cpp = ((kk & 1) * 4 + quad) ^ (n & 7);
            short8 bf = *(const short8*)(kc_lds + (kk >> 1) * 8192 + n * 64 + cpp * 8);
            eh_acc[0][h] = __builtin_amdgcn_mfma_f32_16x16x32_bf16(a0, bf, eh_acc[0][h], 0, 0, 0);
            eh_acc[1][h] = __builtin_amdgcn_mfma_f32_16x16x32_bf16(a1, bf, eh_acc[1][h], 0, 0, 0);
        }
    }
    __syncthreads();   // B1: Eh LDS reads done; kc_lds/ww_lds reusable

    // ---- w generation helper state ----
    const float sr = s_lds[r_w];
    const float mr = m_lds[r_w];
    float denom_part = 0.f;

    auto genw = [&](int jt, ushort_t* wb) {
        const int jb = jt * TJ + jg * 8;
        float4 ta = *(const float4*)(t_lds + jb);
        float4 tb = *(const float4*)(t_lds + jb + 4);
        float tv[8] = {ta.x, ta.y, ta.z, ta.w, tb.x, tb.y, tb.z, tb.w};
        unsigned mb = msk[jt >> 2] >> ((jt & 3) * 8);
        float wv[8];
        #pragma unroll
        for (int e = 0; e < 8; ++e) {
            float x = sr + tv[e];
            x = fmaxf(x, LEAKY_S * x);
            float w = __expf(x - mr);
            w = ((mb >> e) & 1u) ? w : 0.f;
            denom_part += w;
            wv[e] = w;
        }
        unsigned pk[4];
        #pragma unroll
        for (int i = 0; i < 4; ++i) {
            unsigned ua = __float_as_uint(wv[2 * i + 0]) + 0x8000u;
            unsigned ub = __float_as_uint(wv[2 * i + 1]) + 0x8000u;
            pk[i] = __builtin_amdgcn_perm(ub, ua, 0x07060302);
        }
        *(uint4*)(wb + r_w * WST + jg * 8) = make_uint4(pk[0], pk[1], pk[2], pk[3]);
    };

    // ---- pipeline prologue: kc[0] async + w[0] ----
    #pragma unroll
    for (int u = 0; u < 4; ++u) {
        int ci = u * 256 + tid;
        async16(kc_sw + ci * 8, kc_lds + ci * 8);
    }
    genw(0, ww_lds);
    __syncthreads();   // B2: kc[0] + w[0] ready

    // ---- main j loop: 16 tiles, one barrier each, double-buffered ----
    for (int jt = 0; jt < N_KCC / TJ; ++jt) {
        if (jt < 15) {
            const ushort_t* gsrc = kc_sw + (size_t)(jt + 1) * 8192;
            ushort_t* kdst = kc_lds + ((jt + 1) & 1) * 8192;
            #pragma unroll
            for (int u = 0; u < 4; ++u) {
                int ci = u * 256 + tid;
                async16(gsrc + ci * 8, kdst + ci * 8);
            }
            genw(jt + 1, ww_lds + ((jt + 1) & 1) * 2304);
        }
        const ushort_t* kcb = kc_lds + (jt & 1) * 8192;
        const ushort_t* wb  = ww_lds + (jt & 1) * 2304;
        #pragma unroll
        for (int kk = 0; kk < 2; ++kk) {
            short8 a0 = *(const short8*)(wb + l15 * WST + kk * 32 + quad * 8);
            short8 a1 = *(const short8*)(wb + (16 + l15) * WST + kk * 32 + quad * 8);
            #pragma unroll
            for (int h = 0; h < 2; ++h) {
                const int f = (h * 4 + wid) * 16 + l15;
                const int cpp = (kk * 4 + quad) ^ (f & 7);
                short8 bf = *(const short8*)(kcb + f * 64 + cpp * 8);
                att_acc[0][h] = __builtin_amdgcn_mfma_f32_16x16x32_bf16(a0, bf, att_acc[0][h], 0, 0, 0);
                att_acc[1][h] = __builtin_amdgcn_mfma_f32_16x16x32_bf16(a1, bf, att_acc[1][h], 0, 0, 0);
            }
        }
        __syncthreads();   // next tile's kc/w ready; this tile's reads done
    }

    // ---- denominator reduce ----
    scrD[tid] = denom_part;
    __syncthreads();
    if (tid < BR) {
        float d = 0.f;
        #pragma unroll
        for (int g = 0; g < 8; ++g) d += scrD[tid * 8 + g];
        denom_lds[tid] = (d > 0.f) ? d : 1.f;
    }
    __syncthreads();

    // ---- epilogue: normalize * Eh, elu, store (C-layout: col=l15, row=quad*4+reg) ----
    #pragma unroll
    for (int mg = 0; mg < 2; ++mg) {
        float rd[4];
        #pragma unroll
        for (int reg = 0; reg < 4; ++reg)
            rd[reg] = 1.f / denom_lds[mg * 16 + quad * 4 + reg];
        #pragma unroll
        for (int h = 0; h < 2; ++h) {
            const int col = (h * 4 + wid) * 16 + l15;
            #pragma unroll
            for (int reg = 0; reg < 4; ++reg) {
                const int rl = mg * 16 + quad * 4 + reg;
                float v = att_acc[mg][h][reg] * rd[reg] * eh_acc[mg][h][reg];
                out[(size_t)(R0 + rl) * FDIM + col] = (v > 0.f) ? v : expm1f(v);
            }
        }
    }
}

extern "C" void kernel_launch(void* const* d_in, const int* in_sizes, int n_in,
                              void* d_out, int out_size, void* d_ws, size_t ws_size,
                              hipStream_t stream)
{
    const float* ex_h = (const float*)d_in[0];
    const float* kc_h = (const float*)d_in[1];
    const int*   adj  = (const int*)d_in[2];
    const float* W1   = (const float*)d_in[3];
    const float* E    = (const float*)d_in[4];
    const float* a    = (const float*)d_in[5];
    float* outp = (float*)d_out;
    float* ws   = (float*)d_ws;

    gat_setup<<<2502, 256, 0, stream>>>(adj, W1, E, a, ws);
    gat_prep1<<<64, 256, 0, stream>>>(kc_h, a, ws);
    gat_main<<<N_EXC / BR, 256, 0, stream>>>(ex_h, ws, outp);
}

// Round 9
// 162.231 us; speedup vs baseline: 1.0697x; 1.0271x over previous
//
#include <hip/hip_runtime.h>
#include <math.h>

#define N_EXC   20000
#define N_KCC   1024
#define FDIM    128
#define LEAKY_S 0.2f

#define BR  32       // exercise rows per block
#define TJ  64       // kc (j) tile (16 tiles), double-buffered
#define EXS 136      // ex staging stride in ushorts (272 B)
#define WST 72       // w tile stride in ushorts (144 B)

typedef unsigned short ushort_t;
typedef __attribute__((ext_vector_type(8))) short short8;
typedef __attribute__((ext_vector_type(4))) float floatx4;

__device__ __forceinline__ ushort_t f2bf(float f) {
    unsigned u = __float_as_uint(f);
    u += 0x7FFF + ((u >> 16) & 1);          // RNE
    return (ushort_t)(u >> 16);
}

// async global->LDS, 16 B per lane. LDS dest must be wave-uniform base + lane*16.
__device__ __forceinline__ void async16(const void* g, void* l) {
    __builtin_amdgcn_global_load_lds(
        (const __attribute__((address_space(1))) unsigned int*)g,
        (__attribute__((address_space(3))) unsigned int*)l,
        16, 0, 0);
}

// ws layout (float offsets):
//   [0)     tarr  1024 f32
//   [1024)  w1a1  128 f32
//   [1152)  kc_sw 131072 ushorts (256 KB): 16 tiles x [f=128][c'=8][e=8],
//           tile jt = j>>6, chunk c = (j&63)>>3, c' = c ^ (f&7), val = bf16(kcWh[j][f])
//   [+256K) E_sw  16384 ushorts (32 KB): 2 halves (k<64, k>=64) x [n=128][c'=8][e=8]
//   [+32K)  W1T_sw 16384 ushorts (32 KB): [f=128][c'=16][e=8], c' = c ^ (f&15)

// -------- setup: W1 transpose/w1a1 (b==0) + E swizzle (b==1). adj handled in main (R9).
__global__ __launch_bounds__(256) void gat_setup(const float* __restrict__ W1,
                                                 const float* __restrict__ E,
                                                 const float* __restrict__ a,
                                                 float* __restrict__ ws)
{
    float* w1a1 = ws + N_KCC;
    ushort_t* kc_sw  = (ushort_t*)(ws + N_KCC + FDIM);
    ushort_t* E_sw   = kc_sw + FDIM * N_KCC;
    ushort_t* W1T_sw = E_sw + FDIM * FDIM;

    __shared__ __align__(16) float w1f[128 * 132];   // 67.6 KB
    __shared__ float a_lds[2 * FDIM];

    const int tid = threadIdx.x;

    if (blockIdx.x == 1) {
        // ---- E_sw, two k-halves, c' = ((k&63)>>3) ^ (n&7) ----
        #pragma unroll
        for (int u = 0; u < 8; ++u) {
            int ch = u * 256 + tid;              // 0..2047 chunks
            int half = ch >> 10;
            int rem = ch & 1023;
            int n = rem >> 3, cpp = rem & 7;
            int c = cpp ^ (n & 7);
            int kbase = half * 64 + c * 8;
            unsigned pk[4];
            #pragma unroll
            for (int i = 0; i < 4; ++i) {
                float e0 = E[(kbase + 2 * i + 0) * FDIM + n];
                float e1 = E[(kbase + 2 * i + 1) * FDIM + n];
                pk[i] = (unsigned)f2bf(e0) | ((unsigned)f2bf(e1) << 16);
            }
            *(uint4*)(E_sw + ch * 8) = make_uint4(pk[0], pk[1], pk[2], pk[3]);
        }
        return;
    }

    // ---- b == 0: W1 -> LDS (fp32), transposed swizzled bf16 to ws; w1a1 ----
    #pragma unroll
    for (int u = 0; u < 16; ++u) {
        int flat = u * 256 + tid;
        int k = flat >> 5, c4 = (flat & 31) * 4;
        float4 v = *(const float4*)(W1 + k * FDIM + c4);
        w1f[k * 132 + c4 + 0] = v.x; w1f[k * 132 + c4 + 1] = v.y;
        w1f[k * 132 + c4 + 2] = v.z; w1f[k * 132 + c4 + 3] = v.w;
    }
    a_lds[tid] = a[tid];
    __syncthreads();
    #pragma unroll
    for (int u = 0; u < 8; ++u) {
        int ch = u * 256 + tid;          // 0..2047
        int f = ch >> 4, c = ch & 15;
        unsigned pk[4];
        #pragma unroll
        for (int i = 0; i < 4; ++i) {
            float v0 = w1f[(c * 8 + 2 * i + 0) * 132 + f];
            float v1 = w1f[(c * 8 + 2 * i + 1) * 132 + f];
            pk[i] = (unsigned)f2bf(v0) | ((unsigned)f2bf(v1) << 16);
        }
        *(uint4*)(W1T_sw + f * 128 + (c ^ (f & 15)) * 8) = make_uint4(pk[0], pk[1], pk[2], pk[3]);
    }
    if (tid < FDIM) {
        float acc = 0.f;
        #pragma unroll 8
        for (int f = 0; f < FDIM; ++f) acc += w1f[tid * 132 + f] * a_lds[f];
        w1a1[tid] = acc;
    }
}

// ---------------- prep1: kcWh via MFMA + fused t[j] ----------------
__global__ __launch_bounds__(256) void gat_prep1(const float* __restrict__ kc_h,
                                                 const float* __restrict__ a,
                                                 float* __restrict__ ws)
{
    float* tarr = ws;
    ushort_t* kc_sw  = (ushort_t*)(ws + N_KCC + FDIM);
    ushort_t* E_sw   = kc_sw + FDIM * N_KCC;
    const ushort_t* W1T_sw = E_sw + FDIM * FDIM;

    __shared__ __align__(16) ushort_t w1t[128 * 128];   // 32 KB pre-swizzled
    __shared__ __align__(16) ushort_t outt[128 * 16];   // 4 KB  [f][j-local]
    __shared__ float a2_lds[FDIM];
    __shared__ float scrT[256];

    const int tid = threadIdx.x;
    const int b = blockIdx.x;
    const int j0 = b * 16;
    const int jt = b >> 2;
    const int c0 = (b & 3) * 2;
    const int lane = tid & 63, w = tid >> 6;
    const int l15 = lane & 15, quad = lane >> 4;

    // async-stage W1T (flat copy, pre-swizzled)
    #pragma unroll
    for (int u = 0; u < 8; ++u) {
        int ci = u * 256 + tid;
        async16(W1T_sw + ci * 8, w1t + ci * 8);
    }
    if (tid < FDIM) a2_lds[tid] = a[FDIM + tid];

    // B-fragments: kc_h[j0+l15][k] global -> regs -> bf16 (k-contiguous)
    short8 bfrag[4];
    #pragma unroll
    for (int kk = 0; kk < 4; ++kk) {
        const float* p = kc_h + (size_t)(j0 + l15) * FDIM + kk * 32 + quad * 8;
        float4 x = *(const float4*)(p);
        float4 y = *(const float4*)(p + 4);
        float v[8] = {x.x, x.y, x.z, x.w, y.x, y.y, y.z, y.w};
        unsigned pk[4];
        #pragma unroll
        for (int i = 0; i < 4; ++i)
            pk[i] = (unsigned)f2bf(v[2 * i]) | ((unsigned)f2bf(v[2 * i + 1]) << 16);
        uint4 q = make_uint4(pk[0], pk[1], pk[2], pk[3]);
        bfrag[kk] = *(const short8*)&q;
    }
    __syncthreads();   // drains W1T async + a2 stage

    // C[m=f-local][n=j-local] = sum_k W1[k][f] * kc[j][k]
    floatx4 acc[2];
    acc[0] = (floatx4){0.f, 0.f, 0.f, 0.f};
    acc[1] = (floatx4){0.f, 0.f, 0.f, 0.f};
    #pragma unroll
    for (int kk = 0; kk < 4; ++kk) {
        #pragma unroll
        for (int g = 0; g < 2; ++g) {
            int f = w * 32 + g * 16 + l15;
            int cp = (kk * 4 + quad) ^ l15;
            short8 af = *(const short8*)(w1t + f * 128 + cp * 8);
            acc[g] = __builtin_amdgcn_mfma_f32_16x16x32_bf16(af, bfrag[kk], acc[g], 0, 0, 0);
        }
    }

    // epilogue: bf16 transpose tile + fused t partials
    float tp = 0.f;
    #pragma unroll
    for (int g = 0; g < 2; ++g)
        #pragma unroll
        for (int reg = 0; reg < 4; ++reg) {
            int f = w * 32 + g * 16 + quad * 4 + reg;
            outt[f * 16 + l15] = f2bf(acc[g][reg]);
            tp += acc[g][reg] * a2_lds[f];
        }
    scrT[l15 * 16 + w * 4 + quad] = tp;
    __syncthreads();

    // coalesced swizzled stores to kc_sw
    {
        int f = tid >> 1, hf = tid & 1;
        uint4 v = *(const uint4*)(outt + f * 16 + hf * 8);
        int cp = (c0 + hf) ^ (f & 7);
        *(uint4*)(kc_sw + (size_t)jt * 8192 + f * 64 + cp * 8) = v;
    }
    if (tid < 16) {
        float s = 0.f;
        #pragma unroll
        for (int p = 0; p < 16; ++p) s += scrT[tid * 16 + p];
        tarr[j0 + tid] = s;
    }
}

// ---------------- main ----------------
__global__ __launch_bounds__(256, 3) void gat_main(const float* __restrict__ ex_h,
                                                   const int* __restrict__ adj,
                                                   const float* __restrict__ ws,
                                                   float* __restrict__ out)
{
    const float* tarr = ws;
    const float* w1a1 = ws + N_KCC;
    const ushort_t* kc_sw = (const ushort_t*)(ws + N_KCC + FDIM);
    const ushort_t* E_sw  = kc_sw + FDIM * N_KCC;

    __shared__ __align__(16) float t_lds[N_KCC];          // 4 KB
    __shared__ __align__(16) ushort_t kc_lds[2 * 8192];   // 32 KB (E prologue / kc dbuf)
    __shared__ __align__(16) ushort_t ww_lds[4608];       // 9.2 KB (ex staging / w dbuf)
    __shared__ __align__(16) float scrA[BR];              // per-row s partials
    __shared__ __align__(16) float scrD[256];             // denom partials
    __shared__ float scrB[4];                             // per-wave t-max
    __shared__ float s_lds[BR], m_lds[BR], denom_lds[BR];

    const int tid  = threadIdx.x;
    const int R0   = blockIdx.x * BR;
    const int lane = tid & 63, wid = tid >> 6;
    const int l15  = lane & 15, quad = lane >> 4;

    // ---- issue E async load first (32 KB flat) ----
    #pragma unroll
    for (int u = 0; u < 8; ++u) {
        int ci = u * 256 + tid;
        async16(E_sw + ci * 8, kc_lds + ci * 8);
    }

    // ---- adj prefetch, 3 tiles deep (HBM latency hidden behind prologue/Eh) ----
    const int r_w = tid >> 3;          // w row
    const int jg  = tid & 7;           // 8-j chunk within tile
    const int* aptr = adj + (size_t)(R0 + r_w) * N_KCC + jg * 8;
    int4 t0A = *(const int4*)(aptr);            // tile 0
    int4 t0B = *(const int4*)(aptr + 4);
    int4 pA1 = *(const int4*)(aptr + 64);       // tile 1 -> slot 1 (tile&1)
    int4 pB1 = *(const int4*)(aptr + 68);
    int4 pA0 = *(const int4*)(aptr + 128);      // tile 2 -> slot 0
    int4 pB0 = *(const int4*)(aptr + 132);

    // ---- stage t (with running max), ex rows ----
    float tmx = -1e30f;
    #pragma unroll
    for (int u = 0; u < 4; ++u) {
        float tv = tarr[u * 256 + tid];
        t_lds[u * 256 + tid] = tv;
        tmx = fmaxf(tmx, tv);
    }
    const int r0 = tid >> 3;
    const int fc = (tid & 7) * 16;
    float exv[16];
    {
        const float* src = ex_h + (size_t)(R0 + r0) * FDIM + fc;
        #pragma unroll
        for (int c = 0; c < 4; ++c) {
            float4 v = *(const float4*)(src + c * 4);
            exv[c * 4 + 0] = v.x; exv[c * 4 + 1] = v.y;
            exv[c * 4 + 2] = v.z; exv[c * 4 + 3] = v.w;
        }
        unsigned pk[8];
        #pragma unroll
        for (int i = 0; i < 8; ++i)
            pk[i] = (unsigned)f2bf(exv[2 * i]) | ((unsigned)f2bf(exv[2 * i + 1]) << 16);
        *(uint4*)(ww_lds + r0 * EXS + fc)     = make_uint4(pk[0], pk[1], pk[2], pk[3]);
        *(uint4*)(ww_lds + r0 * EXS + fc + 8) = make_uint4(pk[4], pk[5], pk[6], pk[7]);
    }

    // ---- Tmax: wave shfl-reduce; s-partials: width-8 shfl-reduce ----
    #pragma unroll
    for (int d = 32; d > 0; d >>= 1)
        tmx = fmaxf(tmx, __shfl_down(tmx, d, 64));
    if (lane == 0) scrB[wid] = tmx;
    {
        float p = 0.f;
        #pragma unroll
        for (int i = 0; i < 16; ++i) p += exv[i] * w1a1[fc + i];   // w1a1 from L2 (512 B, hot)
        p += __shfl_down(p, 4, 8);
        p += __shfl_down(p, 2, 8);
        p += __shfl_down(p, 1, 8);
        if ((tid & 7) == 0) scrA[r0] = p;
    }
    __syncthreads();   // S1: drains E async; publishes t/ex LDS, scrA/scrB

    if (tid < BR) {
        float Tm = fmaxf(fmaxf(scrB[0], scrB[1]), fmaxf(scrB[2], scrB[3]));
        float s = scrA[tid];
        s_lds[tid] = s;
        float x = s + Tm;
        m_lds[tid] = (x >= 0.f) ? x : LEAKY_S * x;
    }
    __syncthreads();   // S2: publish s_lds/m_lds (R3 lesson: required)

    // ---- Eh = ex @ E via MFMA (E in kc_lds both halves, swizzled) ----
    floatx4 eh_acc[2][2], att_acc[2][2];
    #pragma unroll
    for (int mg = 0; mg < 2; ++mg)
        #pragma unroll
        for (int h = 0; h < 2; ++h) {
            eh_acc[mg][h]  = (floatx4){0.f, 0.f, 0.f, 0.f};
            att_acc[mg][h] = (floatx4){0.f, 0.f, 0.f, 0.f};
        }
    #pragma unroll
    for (int kk = 0; kk < 4; ++kk) {
        short8 a0 = *(const short8*)(ww_lds + l15 * EXS + kk * 32 + quad * 8);
        short8 a1 = *(const short8*)(ww_lds + (16 + l15) * EXS + kk * 32 + quad * 8);
        #pragma unroll
        for (int h = 0; h < 2; ++h) {
            const int n = (h * 4 + wid) * 16 + l15;
            const int cpp = ((kk & 1) * 4 + quad) ^ (n & 7);
            short8 bf = *(const short8*)(kc_lds + (kk >> 1) * 8192 + n * 64 + cpp * 8);
            eh_acc[0][h] = __builtin_amdgcn_mfma_f32_16x16x32_bf16(a0, bf, eh_acc[0][h], 0, 0, 0);
            eh_acc[1][h] = __builtin_amdgcn_mfma_f32_16x16x32_bf16(a1, bf, eh_acc[1][h], 0, 0, 0);
        }
    }
    __syncthreads();   // B1: Eh LDS reads done; kc_lds/ww_lds reusable

    // ---- w generation helper state ----
    const float sr = s_lds[r_w];
    const float mr = m_lds[r_w];
    float denom_part = 0.f;

    auto genw = [&](int jt, int4 cA, int4 cB, ushort_t* wb) {
        const int jb = jt * TJ + jg * 8;
        float4 ta = *(const float4*)(t_lds + jb);
        float4 tb = *(const float4*)(t_lds + jb + 4);
        float tv[8] = {ta.x, ta.y, ta.z, ta.w, tb.x, tb.y, tb.z, tb.w};
        int av[8] = {cA.x, cA.y, cA.z, cA.w, cB.x, cB.y, cB.z, cB.w};
        float wv[8];
        #pragma unroll
        for (int e = 0; e < 8; ++e) {
            float x = sr + tv[e];
            x = fmaxf(x, LEAKY_S * x);
            float w = __expf(x - mr);
            w = (av[e] > 0) ? w : 0.f;
            denom_part += w;
            wv[e] = w;
        }
        unsigned pk[4];
        #pragma unroll
        for (int i = 0; i < 4; ++i) {
            unsigned ua = __float_as_uint(wv[2 * i + 0]) + 0x8000u;
            unsigned ub = __float_as_uint(wv[2 * i + 1]) + 0x8000u;
            pk[i] = __builtin_amdgcn_perm(ub, ua, 0x07060302);
        }
        *(uint4*)(wb + r_w * WST + jg * 8) = make_uint4(pk[0], pk[1], pk[2], pk[3]);
    };

    // ---- pipeline prologue: kc[0] async + w[0] ----
    #pragma unroll
    for (int u = 0; u < 4; ++u) {
        int ci = u * 256 + tid;
        async16(kc_sw + ci * 8, kc_lds + ci * 8);
    }
    genw(0, t0A, t0B, ww_lds);
    __syncthreads();   // B2: kc[0] + w[0] ready

    // ---- main j loop: 16 tiles, one barrier each, double-buffered ----
    // adj pipeline: slot (tile&1); iteration jt consumes tile jt+1, issues tile jt+3
    // (each adj load has ~2 iterations in flight -> covers ~900-cyc HBM latency).
    #pragma unroll
    for (int jt = 0; jt < N_KCC / TJ; ++jt) {
        if (jt < 15) {
            const ushort_t* gsrc = kc_sw + (size_t)(jt + 1) * 8192;
            ushort_t* kdst = kc_lds + ((jt + 1) & 1) * 8192;
            #pragma unroll
            for (int u = 0; u < 4; ++u) {
                int ci = u * 256 + tid;
                async16(gsrc + ci * 8, kdst + ci * 8);
            }
            // consume adj tile jt+1 from its parity slot
            int4 cA = ((jt + 1) & 1) ? pA1 : pA0;
            int4 cB = ((jt + 1) & 1) ? pB1 : pB0;
            // issue adj tile jt+3 into the same slot it vacates
            if (jt < 13) {
                const int4* np = (const int4*)(aptr + (jt + 3) * 64);
                if ((jt + 1) & 1) { pA1 = np[0]; pB1 = *(const int4*)(aptr + (jt + 3) * 64 + 4); }
                else              { pA0 = np[0]; pB0 = *(const int4*)(aptr + (jt + 3) * 64 + 4); }
            }
            genw(jt + 1, cA, cB, ww_lds + ((jt + 1) & 1) * 2304);
        }
        const ushort_t* kcb = kc_lds + (jt & 1) * 8192;
        const ushort_t* wb  = ww_lds + (jt & 1) * 2304;
        #pragma unroll
        for (int kk = 0; kk < 2; ++kk) {
            short8 a0 = *(const short8*)(wb + l15 * WST + kk * 32 + quad * 8);
            short8 a1 = *(const short8*)(wb + (16 + l15) * WST + kk * 32 + quad * 8);
            #pragma unroll
            for (int h = 0; h < 2; ++h) {
                const int f = (h * 4 + wid) * 16 + l15;
                const int cpp = (kk * 4 + quad) ^ (f & 7);
                short8 bf = *(const short8*)(kcb + f * 64 + cpp * 8);
                att_acc[0][h] = __builtin_amdgcn_mfma_f32_16x16x32_bf16(a0, bf, att_acc[0][h], 0, 0, 0);
                att_acc[1][h] = __builtin_amdgcn_mfma_f32_16x16x32_bf16(a1, bf, att_acc[1][h], 0, 0, 0);
            }
        }
        __syncthreads();   // next tile's kc/w ready; this tile's reads done
    }

    // ---- denominator reduce ----
    scrD[tid] = denom_part;
    __syncthreads();
    if (tid < BR) {
        float d = 0.f;
        #pragma unroll
        for (int g = 0; g < 8; ++g) d += scrD[tid * 8 + g];
        denom_lds[tid] = (d > 0.f) ? d : 1.f;
    }
    __syncthreads();

    // ---- epilogue: normalize * Eh, elu, store (C-layout: col=l15, row=quad*4+reg) ----
    #pragma unroll
    for (int mg = 0; mg < 2; ++mg) {
        float rd[4];
        #pragma unroll
        for (int reg = 0; reg < 4; ++reg)
            rd[reg] = 1.f / denom_lds[mg * 16 + quad * 4 + reg];
        #pragma unroll
        for (int h = 0; h < 2; ++h) {
            const int col = (h * 4 + wid) * 16 + l15;
            #pragma unroll
            for (int reg = 0; reg < 4; ++reg) {
                const int rl = mg * 16 + quad * 4 + reg;
                float v = att_acc[mg][h][reg] * rd[reg] * eh_acc[mg][h][reg];
                out[(size_t)(R0 + rl) * FDIM + col] = (v > 0.f) ? v : expm1f(v);
            }
        }
    }
}

extern "C" void kernel_launch(void* const* d_in, const int* in_sizes, int n_in,
                              void* d_out, int out_size, void* d_ws, size_t ws_size,
                              hipStream_t stream)
{
    const float* ex_h = (const float*)d_in[0];
    const float* kc_h = (const float*)d_in[1];
    const int*   adj  = (const int*)d_in[2];
    const float* W1   = (const float*)d_in[3];
    const float* E    = (const float*)d_in[4];
    const float* a    = (const float*)d_in[5];
    float* outp = (float*)d_out;
    float* ws   = (float*)d_ws;

    gat_setup<<<2, 256, 0, stream>>>(W1, E, a, ws);
    gat_prep1<<<64, 256, 0, stream>>>(kc_h, a, ws);
    gat_main<<<N_EXC / BR, 256, 0, stream>>>(ex_h, adj, ws, outp);
}